// Round 5
// baseline (2626.558 us; speedup 1.0000x reference)
//
#include <hip/hip_runtime.h>

#define DEVI __device__ __forceinline__
typedef float f2 __attribute__((ext_vector_type(2)));

// ---------------- problem constants ----------------
constexpr int T_ = 4096, B_ = 128;
constexpr int CH = 8, NCH = T_ / CH;   // 512 chunks of 8 timesteps
constexpr int NSTAGE = 15;             // proj(d=0) ... tail(d=14)
constexpr int NSTEP = NCH + NSTAGE;    // 527 supersteps
constexpr int XROW = 68;               // x row padded 64->68 dwords

// LDS ring strides (floats).
// y1/xw tt-block [3][20]: row = sl*Y1S + tt*Y1T + g*20 + j
constexpr int Y1T = 60, Y1S = CH * Y1T, Y1L = 2 * Y1S;
// y2 tt-block [3][12]
constexpr int Y2T = 36, Y2S = CH * Y2T, Y2L = 2 * Y2S;

struct P {
  const float* x;
  const float* w1; const float* b1;    // wih0 (20x64), bih0 (20)
  const float* wih[31]; const float* whh[31];
  const float* bih[31]; const float* bhh[31];
  float* out;
};

DEVI float ftanh(float x) {
  // tanh(x) = 1 - 2/(exp2(2*log2e*x)+1); ~1ulp, maps +-Inf -> +-1
  float e = __builtin_amdgcn_exp2f(x * 2.8853900817779268f);
  return 1.0f - 2.0f * __builtin_amdgcn_rcpf(e + 1.0f);
}

DEVI f2 pfma(f2 a, f2 b, f2 c) { return __builtin_elementwise_fma(a, b, c); }

// 20-float dot: 5 ds_read_b128 + 10 v_pk_fma_f32
DEVI void acc20(f2& a, const float* r, const f2* w) {
#pragma unroll
  for (int q = 0; q < 5; q++) {
    float4 v = ((const float4*)r)[q];
    union { float4 f; f2 h[2]; } u; u.f = v;
    a = pfma(u.h[0], w[2 * q], a);
    a = pfma(u.h[1], w[2 * q + 1], a);
  }
}

// 10-float dot: 2 b128 + 1 b64 + 5 v_pk_fma_f32
DEVI void acc10(f2& a, const float* r, const f2* w) {
  float4 v0 = ((const float4*)r)[0];
  float4 v1 = ((const float4*)r)[1];
  float2 v2 = *(const float2*)(r + 8);
  union { float4 f; f2 h[2]; } u0, u1; u0.f = v0; u1.f = v1;
  f2 t; t.x = v2.x; t.y = v2.y;
  a = pfma(u0.h[0], w[0], a);
  a = pfma(u0.h[1], w[1], a);
  a = pfma(u1.h[0], w[2], a);
  a = pfma(u1.h[1], w[3], a);
  a = pfma(t, w[4], a);
}

// ===== wave 0: global->LDS x staging only. Register double-buffer: the
// chunk written to LDS this superstep was loaded LAST superstep, so the
// vmcnt drain at the barrier never exposes HBM latency. =====
DEVI void stage_x(const P& p, int wg, int lane, float* xb) {
  const float* src[6]; int dst[6];
#pragma unroll
  for (int r = 0; r < 6; r++) {
    int f = lane + 64 * r;             // 384 float4 per chunk (CH*3*64 floats)
    int tq = f / 48, rem = f % 48, gg = rem / 16, qq = rem % 16;
    int b = wg * 3 + gg; if (b > B_ - 1) b = B_ - 1;
    src[r] = p.x + (size_t)(tq * B_ + b) * 64 + qq * 4;
    dst[r] = (tq * 3 + gg) * XROW + qq * 4;
  }
  float4 pf[6];
#pragma unroll
  for (int r = 0; r < 6; r++) pf[r] = *(const float4*)src[r];     // chunk 0
#pragma unroll
  for (int r = 0; r < 6; r++) *(float4*)(xb + dst[r]) = pf[r];    // -> slot 0
#pragma unroll
  for (int r = 0; r < 6; r++) src[r] += (size_t)CH * B_ * 64;
#pragma unroll
  for (int r = 0; r < 6; r++) pf[r] = *(const float4*)src[r];     // chunk 1 in flight
#pragma unroll
  for (int r = 0; r < 6; r++) src[r] += (size_t)CH * B_ * 64;

  __syncthreads();   // pre-barrier (chunk 0 visible)
  for (int s = 0; s < NSTEP; s++) {
    const int c = s;
    if (c + 1 < NCH) {
      float* db = xb + ((c + 1) & 1) * (CH * 3 * XROW);
#pragma unroll
      for (int r = 0; r < 6; r++) *(float4*)(db + dst[r]) = pf[r];
      if (c + 2 < NCH) {
#pragma unroll
        for (int r = 0; r < 6; r++) pf[r] = *(const float4*)src[r];
#pragma unroll
        for (int r = 0; r < 6; r++) src[r] += (size_t)CH * B_ * 64;
      }
    }
    __syncthreads();
  }
}

// ===== wave 1: input projection (64 -> 20), d=0 =====
DEVI void proj(const P& p, int lane, const float* xb, float* xw) {
  const int g = (lane < 60) ? lane / 20 : 2;
  const int j = lane % 20;
  const bool wr = lane < 60;
  f2 wp[32];
#pragma unroll
  for (int k = 0; k < 32; k++) {
    wp[k].x = p.w1[j * 64 + 2 * k]; wp[k].y = p.w1[j * 64 + 2 * k + 1];
  }
  const float bp = p.b1[j];

  __syncthreads();
  for (int s = 0; s < NSTEP; s++) {
    const int c = s;
    if (c < NCH) {
      const int sl = c & 1;
      const float* base = xb + sl * (CH * 3 * XROW) + g * XROW;
      float* ob = xw + sl * Y1S + g * 20 + j;
      for (int tt = 0; tt < CH; tt++) {
        const float* xr = base + tt * (3 * XROW);
        f2 a; a.x = bp; a.y = 0.f;
#pragma unroll
        for (int q = 0; q < 16; q++) {
          float4 v = ((const float4*)xr)[q];
          union { float4 f; f2 h[2]; } u; u.f = v;
          a = pfma(u.h[0], wp[2 * q], a);
          a = pfma(u.h[1], wp[2 * q + 1], a);
        }
        if (wr) ob[tt * Y1T] = a.x + a.y;
      }
    }
    __syncthreads();
  }
}

// ===== waves 2..11: two H=20 layers each =====
template <bool FIRST>
DEVI void pair(int la, int d, const P& p, int lane, float* y1f, const float* xw) {
  const int g = (lane < 60) ? lane / 20 : 2;
  const int j = lane % 20;
  const bool wr = lane < 60;
  const int lb = la + 1;
  f2 whA[10], whB[10], wiB[10], wiA[FIRST ? 1 : 10];
#pragma unroll
  for (int k = 0; k < 10; k++) {
    whA[k].x = p.whh[la][j * 20 + 2 * k]; whA[k].y = p.whh[la][j * 20 + 2 * k + 1];
    whB[k].x = p.whh[lb][j * 20 + 2 * k]; whB[k].y = p.whh[lb][j * 20 + 2 * k + 1];
    wiB[k].x = p.wih[lb][j * 20 + 2 * k]; wiB[k].y = p.wih[lb][j * 20 + 2 * k + 1];
  }
  if constexpr (!FIRST) {
#pragma unroll
    for (int k = 0; k < 10; k++) {
      wiA[k].x = p.wih[la][j * 20 + 2 * k]; wiA[k].y = p.wih[la][j * 20 + 2 * k + 1];
    }
  }
  float bA = p.bhh[la][j];
  if constexpr (!FIRST) bA += p.bih[la][j];   // L0: bih folded into projection
  const float bB = p.bih[lb][j] + p.bhh[lb][j];

  const float* yin = FIRST ? (xw + g * 20 + j) : (y1f + (la - 1) * Y1L + g * 20);
  const float* yAr = y1f + la * Y1L + g * 20;
  float*       yAw = y1f + la * Y1L + g * 20 + j;
  const float* yBr = y1f + lb * Y1L + g * 20;
  float*       yBw = y1f + lb * Y1L + g * 20 + j;
  if (wr) {  // zero slot[1] last row: read at c==0 as "h_{-1}" = 0
    yAw[Y1S + (CH - 1) * Y1T] = 0.f; yBw[Y1S + (CH - 1) * Y1T] = 0.f;
  }

  __syncthreads();
  for (int s = 0; s < NSTEP; s++) {
    const int c = s - d;
    if ((unsigned)c < (unsigned)NCH) {
      const int sl = c & 1;
      const int SB = sl * Y1S;
      int pv = (1 - sl) * Y1S + (CH - 1) * Y1T;  // prev chunk's last row
      for (int tt = 0; tt < CH; tt++) {
        const int in = SB + tt * Y1T;
        f2 a; a.x = bA; a.y = 0.f;
        if constexpr (FIRST) a.x += yin[in];
        else acc20(a, yin + in, wiA);
        acc20(a, yAr + pv, whA);
        const float hA = ftanh(a.x + a.y);
        if (wr) yAw[in] = hA;
        f2 bb; bb.x = bB; bb.y = 0.f;
        acc20(bb, yAr + in, wiB);    // row just written (same-wave DS order)
        acc20(bb, yBr + pv, whB);
        const float hB = ftanh(bb.x + bb.y);
        if (wr) yBw[in] = hB;
        pv = in;
      }
    }
    __syncthreads();
  }
}

// ===== wave 12: L20 (20->10) + L21 + L22 =====
DEVI void tri20(const P& p, int d, int lane, const float* y1f, float* y2f) {
  const int g = (lane < 60) ? lane / 20 : 2;
  const int j = lane % 20;
  const int jc = j < 10 ? j : 9;
  const bool wr = (lane < 60) && (j < 10);
  f2 wi0[10], wh0[5], wi1[5], wh1[5], wi2[5], wh2[5];
#pragma unroll
  for (int k = 0; k < 10; k++) {
    wi0[k].x = p.wih[20][jc * 20 + 2 * k]; wi0[k].y = p.wih[20][jc * 20 + 2 * k + 1];
  }
#pragma unroll
  for (int k = 0; k < 5; k++) {
    wh0[k].x = p.whh[20][jc * 10 + 2 * k]; wh0[k].y = p.whh[20][jc * 10 + 2 * k + 1];
    wi1[k].x = p.wih[21][jc * 10 + 2 * k]; wi1[k].y = p.wih[21][jc * 10 + 2 * k + 1];
    wh1[k].x = p.whh[21][jc * 10 + 2 * k]; wh1[k].y = p.whh[21][jc * 10 + 2 * k + 1];
    wi2[k].x = p.wih[22][jc * 10 + 2 * k]; wi2[k].y = p.wih[22][jc * 10 + 2 * k + 1];
    wh2[k].x = p.whh[22][jc * 10 + 2 * k]; wh2[k].y = p.whh[22][jc * 10 + 2 * k + 1];
  }
  const float b0 = p.bih[20][jc] + p.bhh[20][jc];
  const float b1 = p.bih[21][jc] + p.bhh[21][jc];
  const float b2 = p.bih[22][jc] + p.bhh[22][jc];

  const float* y19 = y1f + 19 * Y1L + g * 20;
  const float* r0 = y2f + 0 * Y2L + g * 12;  float* w0 = y2f + 0 * Y2L + g * 12 + j;
  const float* r1 = y2f + 1 * Y2L + g * 12;  float* w1 = y2f + 1 * Y2L + g * 12 + j;
  const float* r2 = y2f + 2 * Y2L + g * 12;  float* w2 = y2f + 2 * Y2L + g * 12 + j;
  if (wr) {
    w0[Y2S + (CH - 1) * Y2T] = 0.f; w1[Y2S + (CH - 1) * Y2T] = 0.f;
    w2[Y2S + (CH - 1) * Y2T] = 0.f;
  }

  __syncthreads();
  for (int s = 0; s < NSTEP; s++) {
    const int c = s - d;
    if ((unsigned)c < (unsigned)NCH) {
      const int sl = c & 1;
      const int SB1 = sl * Y1S, SB2 = sl * Y2S;
      int pv = (1 - sl) * Y2S + (CH - 1) * Y2T;
      for (int tt = 0; tt < CH; tt++) {
        const int in1 = SB1 + tt * Y1T, in2 = SB2 + tt * Y2T;
        f2 a; a.x = b0; a.y = 0.f;
        acc20(a, y19 + in1, wi0);
        acc10(a, r0 + pv, wh0);
        float h = ftanh(a.x + a.y);
        if (wr) w0[in2] = h;
        a.x = b1; a.y = 0.f;
        acc10(a, r0 + in2, wi1);
        acc10(a, r1 + pv, wh1);
        h = ftanh(a.x + a.y);
        if (wr) w1[in2] = h;
        a.x = b2; a.y = 0.f;
        acc10(a, r1 + in2, wi2);
        acc10(a, r2 + pv, wh2);
        h = ftanh(a.x + a.y);
        if (wr) w2[in2] = h;
        pv = in2;
      }
    }
    __syncthreads();
  }
}

// ===== waves 13/14: three H=10 layers (l0, l0+1, l0+2) =====
DEVI void tri_s2(int l0, int d, const P& p, int lane, float* y2f) {
  const int g = (lane < 60) ? lane / 20 : 2;
  const int j = lane % 20;
  const int jc = j < 10 ? j : 9;
  const bool wr = (lane < 60) && (j < 10);
  f2 wi[3][5], wh[3][5];
  float bs[3];
#pragma unroll
  for (int m = 0; m < 3; m++) {
    const int l = l0 + m;
#pragma unroll
    for (int k = 0; k < 5; k++) {
      wi[m][k].x = p.wih[l][jc * 10 + 2 * k]; wi[m][k].y = p.wih[l][jc * 10 + 2 * k + 1];
      wh[m][k].x = p.whh[l][jc * 10 + 2 * k]; wh[m][k].y = p.whh[l][jc * 10 + 2 * k + 1];
    }
    bs[m] = p.bih[l][jc] + p.bhh[l][jc];
  }
  const int bi = l0 - 21;
  const float* yi0 = y2f + bi * Y2L + g * 12;
  const float* r0 = y2f + (bi + 1) * Y2L + g * 12;  float* w0 = y2f + (bi + 1) * Y2L + g * 12 + j;
  const float* r1 = y2f + (bi + 2) * Y2L + g * 12;  float* w1 = y2f + (bi + 2) * Y2L + g * 12 + j;
  const float* r2 = y2f + (bi + 3) * Y2L + g * 12;  float* w2 = y2f + (bi + 3) * Y2L + g * 12 + j;
  if (wr) {
    w0[Y2S + (CH - 1) * Y2T] = 0.f; w1[Y2S + (CH - 1) * Y2T] = 0.f;
    w2[Y2S + (CH - 1) * Y2T] = 0.f;
  }

  __syncthreads();
  for (int s = 0; s < NSTEP; s++) {
    const int c = s - d;
    if ((unsigned)c < (unsigned)NCH) {
      const int sl = c & 1;
      const int SB2 = sl * Y2S;
      int pv = (1 - sl) * Y2S + (CH - 1) * Y2T;
      for (int tt = 0; tt < CH; tt++) {
        const int in2 = SB2 + tt * Y2T;
        f2 a; a.x = bs[0]; a.y = 0.f;
        acc10(a, yi0 + in2, wi[0]);
        acc10(a, r0 + pv, wh[0]);
        float h = ftanh(a.x + a.y);
        if (wr) w0[in2] = h;
        a.x = bs[1]; a.y = 0.f;
        acc10(a, r0 + in2, wi[1]);
        acc10(a, r1 + pv, wh[1]);
        h = ftanh(a.x + a.y);
        if (wr) w1[in2] = h;
        a.x = bs[2]; a.y = 0.f;
        acc10(a, r1 + in2, wi[2]);
        acc10(a, r2 + pv, wh[2]);
        h = ftanh(a.x + a.y);
        if (wr) w2[in2] = h;
        pv = in2;
      }
    }
    __syncthreads();
  }
}

// ===== wave 15: L29 (H=10) + L30 (H=1) + stores =====
DEVI void tail(const P& p, int d, int wg, int lane, float* y2f) {
  const int g = (lane < 60) ? lane / 20 : 2;
  const int j = lane % 20;
  const int jc = j < 10 ? j : 9;
  const bool wr = (lane < 60) && (j < 10);
  const int b = wg * 3 + g;
  const bool st = (lane < 60) && (j == 0) && (b < B_);
  f2 wi29[5], wh29[5], wi30[5];
#pragma unroll
  for (int k = 0; k < 5; k++) {
    wi29[k].x = p.wih[29][jc * 10 + 2 * k]; wi29[k].y = p.wih[29][jc * 10 + 2 * k + 1];
    wh29[k].x = p.whh[29][jc * 10 + 2 * k]; wh29[k].y = p.whh[29][jc * 10 + 2 * k + 1];
    wi30[k].x = p.wih[30][2 * k];           wi30[k].y = p.wih[30][2 * k + 1];
  }
  const float b29 = p.bih[29][jc] + p.bhh[29][jc];
  const float b30 = p.bih[30][0] + p.bhh[30][0];
  const float wh30 = p.whh[30][0];
  float h30 = 0.0f;
  const float* r8 = y2f + 8 * Y2L + g * 12;
  const float* r9 = y2f + 9 * Y2L + g * 12;
  float*       w9 = y2f + 9 * Y2L + g * 12 + j;
  if (wr) w9[Y2S + (CH - 1) * Y2T] = 0.f;
  float* optr = p.out + ((b < B_) ? b : (B_ - 1));

  __syncthreads();
  for (int s = 0; s < NSTEP; s++) {
    const int c = s - d;
    if ((unsigned)c < (unsigned)NCH) {
      const int sl = c & 1;
      const int SB2 = sl * Y2S;
      int pv = (1 - sl) * Y2S + (CH - 1) * Y2T;
      for (int tt = 0; tt < CH; tt++) {
        const int in2 = SB2 + tt * Y2T;
        f2 a; a.x = b29; a.y = 0.f;
        acc10(a, r8 + in2, wi29);
        acc10(a, r9 + pv, wh29);
        const float h = ftanh(a.x + a.y);
        if (wr) w9[in2] = h;
        f2 a3; a3.x = b30; a3.y = 0.f;
        acc10(a3, r9 + in2, wi30);
        h30 = ftanh(fmaf(h30, wh30, a3.x + a3.y));
        if (st) optr[(c * CH + tt) * B_] = h30;
        pv = in2;
      }
    }
    __syncthreads();
  }
  if (st) p.out[T_ * B_ + b] = h30;  // hT
}

// ================= kernel =================
__global__ __launch_bounds__(1024, 4) void rnn_fused(P p) {
  __shared__ float xbuf[2 * CH * 3 * XROW];   // 13.1 KB staged x
  __shared__ float xw[Y1L];                   //  3.8 KB projected input ring
  __shared__ float y1[20 * Y1L];              // 76.8 KB stack1 rings
  __shared__ float y2[10 * Y2L];              // 23.0 KB stack2 rings
  const int w = threadIdx.x >> 6, lane = threadIdx.x & 63, wg = blockIdx.x;
  if (w == 0)       stage_x(p, wg, lane, xbuf);
  else if (w == 1)  proj(p, lane, xbuf, xw);
  else if (w == 2)  pair<true>(0, 1, p, lane, y1, xw);
  else if (w <= 11) pair<false>(2 * (w - 2), w - 1, p, lane, y1, xw);
  else if (w == 12) tri20(p, 11, lane, y1, y2);
  else if (w == 13) tri_s2(23, 12, p, lane, y2);
  else if (w == 14) tri_s2(26, 13, p, lane, y2);
  else              tail(p, 14, wg, lane, y2);
}

extern "C" void kernel_launch(void* const* d_in, const int* in_sizes, int n_in,
                              void* d_out, int out_size, void* d_ws, size_t ws_size,
                              hipStream_t stream) {
  (void)in_sizes; (void)out_size; (void)d_ws; (void)ws_size;
  if (n_in < 21) return;
  P p{};
  p.x  = (const float*)d_in[0];
  p.w1 = (const float*)d_in[1];    // s1_wih0 (20x64)
  p.b1 = (const float*)d_in[3];    // s1_bih0
  p.wih[0] = nullptr;              p.whh[0] = (const float*)d_in[2];
  p.bih[0] = nullptr;              p.bhh[0] = (const float*)d_in[4];
  for (int l = 1; l < 20; l++) {
    p.wih[l] = (const float*)d_in[5] + (l - 1) * 400;
    p.whh[l] = (const float*)d_in[6] + (l - 1) * 400;
    p.bih[l] = (const float*)d_in[7] + (l - 1) * 20;
    p.bhh[l] = (const float*)d_in[8] + (l - 1) * 20;
  }
  p.wih[20] = (const float*)d_in[9];   p.whh[20] = (const float*)d_in[10];
  p.bih[20] = (const float*)d_in[11];  p.bhh[20] = (const float*)d_in[12];
  for (int l = 21; l < 30; l++) {
    p.wih[l] = (const float*)d_in[13] + (l - 21) * 100;
    p.whh[l] = (const float*)d_in[14] + (l - 21) * 100;
    p.bih[l] = (const float*)d_in[15] + (l - 21) * 10;
    p.bhh[l] = (const float*)d_in[16] + (l - 21) * 10;
  }
  p.wih[30] = (const float*)d_in[17];  p.whh[30] = (const float*)d_in[18];
  p.bih[30] = (const float*)d_in[19];  p.bhh[30] = (const float*)d_in[20];
  p.out = (float*)d_out;

  rnn_fused<<<43, 1024, 0, stream>>>(p);
}